// Round 11
// baseline (400.155 us; speedup 1.0000x reference)
//
#include <hip/hip_runtime.h>
#include <math.h>

// Problem constants
#define QDIM 512     // 2^9 state dim
#define DD   128     // K*C_IN = input dim of quadratic form
#define LIN  4096
#define LOUT 4089    // (4096 - 7 - 1)/1 + 1
#define NC   16      // C_IN
#define NB   16      // batch
#define NBLK 512     // persistent grid

typedef __attribute__((ext_vector_type(8))) short bf16x8;
typedef __attribute__((ext_vector_type(4))) float f32x4;

// Scratch in device globals (NOT d_ws) — R5 lesson. Every data element is
// rewritten each call before read -> no cross-call state.
__device__ float  g_B[QDIM * DD];
__device__ float  g_C[QDIM * DD];
__device__ unsigned short g_Qh[DD * DD];   // bf16 hi part of Q
__device__ unsigned short g_Ql[DD * DD];   // bf16 residual of Q

// Tree-barrier state. R8 lesson: ONE cache line x 512 serialized cross-XCD
// RMWs ~ 137ns each = 70us/barrier. Tree: 64 leaf lines x 8, 8 mid x 8,
// 1 top x 8 -> serial chain ~24 RMWs ~ 3-4us. Counters self-reset (closer
// zeroes before propagating); gen is monotonic -> replay-safe.
__device__ unsigned g_lvl0[64 * 32];   // 128B-strided lines
__device__ unsigned g_lvl1[8 * 32];
__device__ unsigned g_lvl2;
__device__ unsigned g_gen;

__device__ __forceinline__ void tree_barrier(int bid) {
  __syncthreads();
  if (threadIdx.x == 0) {
    __threadfence();  // release: drain this block's writes to device scope
    unsigned gen = __hip_atomic_load(&g_gen, __ATOMIC_RELAXED,
                                     __HIP_MEMORY_SCOPE_AGENT);
    bool released = false;
    unsigned p0 = __hip_atomic_fetch_add(&g_lvl0[(bid >> 3) * 32], 1u,
                                         __ATOMIC_ACQ_REL, __HIP_MEMORY_SCOPE_AGENT);
    if (p0 == 7u) {
      __hip_atomic_store(&g_lvl0[(bid >> 3) * 32], 0u, __ATOMIC_RELAXED,
                         __HIP_MEMORY_SCOPE_AGENT);
      unsigned p1 = __hip_atomic_fetch_add(&g_lvl1[(bid >> 6) * 32], 1u,
                                           __ATOMIC_ACQ_REL, __HIP_MEMORY_SCOPE_AGENT);
      if (p1 == 7u) {
        __hip_atomic_store(&g_lvl1[(bid >> 6) * 32], 0u, __ATOMIC_RELAXED,
                           __HIP_MEMORY_SCOPE_AGENT);
        unsigned p2 = __hip_atomic_fetch_add(&g_lvl2, 1u,
                                             __ATOMIC_ACQ_REL, __HIP_MEMORY_SCOPE_AGENT);
        if (p2 == 7u) {
          __hip_atomic_store(&g_lvl2, 0u, __ATOMIC_RELAXED,
                             __HIP_MEMORY_SCOPE_AGENT);
          __hip_atomic_store(&g_gen, gen + 1u, __ATOMIC_RELEASE,
                             __HIP_MEMORY_SCOPE_AGENT);
          released = true;
        }
      }
    }
    if (!released) {
      while (__hip_atomic_load(&g_gen, __ATOMIC_ACQUIRE,
                               __HIP_MEMORY_SCOPE_AGENT) == gen) {
        __builtin_amdgcn_s_sleep(2);
      }
    }
    __threadfence();  // acquire: invalidate stale cached lines
  }
  __syncthreads();
}

// ---- bf16 helpers (RNE) ----
__device__ __forceinline__ unsigned short f2bf(float f) {
  union { float f; unsigned u; } v; v.f = f;
  unsigned u = v.u + 0x7FFFu + ((v.u >> 16) & 1u);
  return (unsigned short)(u >> 16);
}
__device__ __forceinline__ float bf2f(unsigned short h) {
  union { unsigned u; float f; } v; v.u = ((unsigned)h) << 16;
  return v.f;
}

// ---------------------------------------------------------------------------
// One persistent kernel, 5 phases (math verbatim from R9 — measured-best):
//  P1 w1: g_B[i] = (R1^T e_i)[0:128]           (512 blocks, 1 row each)
//  P2 mm: g_C[i] = (R2^T e_i)^T g_B            (512 blocks)
//  P3 mm: g_B[i] = (R3^T e_i)^T g_C            (512 blocks)
//  P4 formq: g_Q = A^T S A (A=g_B), bf16 hi/lo (128 blocks)
//  P5 quad: 2 t-tiles of 64 per block (MFMA split-bf16)
// ---------------------------------------------------------------------------

__device__ __forceinline__ void butterfly_T(float* col, const float* theta,
                                            int l, int p) {
  #pragma unroll
  for (int qq = 0; qq < 9; ++qq) {
    int q = 8 - qq;                    // reverse order for transpose
    float half = theta[l * 9 + q] * 0.5f;
    float c = cosf(half), s = sinf(half);
    int right = QDIM >> (q + 1);
    int a = p >> (8 - q);
    int r = p & (right - 1);
    int i0 = (a * 2) * right + r;
    int i1 = i0 + right;
    float v0 = col[i0], v1 = col[i1];
    col[i0] = c * v0 + s * v1;         // transposed 2x2
    col[i1] = c * v1 - s * v0;
    __syncthreads();
  }
}

__global__ __launch_bounds__(256, 2) void fused_kernel(
    const float* __restrict__ x, const float* __restrict__ E,
    const float* __restrict__ theta, float* __restrict__ out) {
  __shared__ float erow[QDIM];
  __shared__ float part[DD];
  __shared__ float xs[NC][72];
  __shared__ float red[2][4][64];    // reused pdot/pnrm staging (unused by MFMA path)
  (void)red;
  int bid = blockIdx.x;
  int tid = threadIdx.x;

  // ---- P1: w1 ----
  {
    int i = bid;
    erow[tid]       = E[i * QDIM + tid];
    erow[tid + 256] = E[i * QDIM + tid + 256];
    __syncthreads();
    butterfly_T(erow, theta, 0, tid);
    if (tid < DD) g_B[i * DD + tid] = erow[tid];
  }
  tree_barrier(bid);

  // ---- P2: mm l=1 : g_C = (R2^T e)^T g_B ----
  {
    int i = bid;
    erow[tid]       = E[i * QDIM + tid];
    erow[tid + 256] = E[i * QDIM + tid + 256];
    __syncthreads();
    butterfly_T(erow, theta, 1, tid);
    int j = tid & 127, h = tid >> 7;
    float a0 = 0.f, a1 = 0.f, a2 = 0.f, a3 = 0.f;
    int m0 = h * 256;
    #pragma unroll 8
    for (int m = m0; m < m0 + 256; m += 4) {
      a0 = fmaf(erow[m + 0], g_B[(m + 0) * DD + j], a0);
      a1 = fmaf(erow[m + 1], g_B[(m + 1) * DD + j], a1);
      a2 = fmaf(erow[m + 2], g_B[(m + 2) * DD + j], a2);
      a3 = fmaf(erow[m + 3], g_B[(m + 3) * DD + j], a3);
    }
    float sum = (a0 + a1) + (a2 + a3);
    __syncthreads();
    if (h == 1) part[j] = sum;
    __syncthreads();
    if (h == 0) g_C[i * DD + j] = sum + part[j];
  }
  tree_barrier(bid);

  // ---- P3: mm l=2 : g_B = (R3^T e)^T g_C ----
  {
    int i = bid;
    erow[tid]       = E[i * QDIM + tid];
    erow[tid + 256] = E[i * QDIM + tid + 256];
    __syncthreads();
    butterfly_T(erow, theta, 2, tid);
    int j = tid & 127, h = tid >> 7;
    float a0 = 0.f, a1 = 0.f, a2 = 0.f, a3 = 0.f;
    int m0 = h * 256;
    #pragma unroll 8
    for (int m = m0; m < m0 + 256; m += 4) {
      a0 = fmaf(erow[m + 0], g_C[(m + 0) * DD + j], a0);
      a1 = fmaf(erow[m + 1], g_C[(m + 1) * DD + j], a1);
      a2 = fmaf(erow[m + 2], g_C[(m + 2) * DD + j], a2);
      a3 = fmaf(erow[m + 3], g_C[(m + 3) * DD + j], a3);
    }
    float sum = (a0 + a1) + (a2 + a3);
    __syncthreads();
    if (h == 1) part[j] = sum;
    __syncthreads();
    if (h == 0) g_B[i * DD + j] = sum + part[j];
  }
  tree_barrier(bid);

  // ---- P4: formq (blocks 0..127) ----
  if (bid < DD) {
    int j1 = bid;
    // reuse erow[0:512] as colA
    for (int i = tid; i < QDIM; i += 256) {
      float sgn = (i < 256) ? 1.0f : -1.0f;
      erow[i] = sgn * g_B[i * DD + j1];
    }
    __syncthreads();
    int j2 = tid & 127, h = tid >> 7;
    float a0 = 0.f, a1 = 0.f, a2 = 0.f, a3 = 0.f;
    int i0 = h * 256;
    #pragma unroll 8
    for (int i = i0; i < i0 + 256; i += 4) {
      a0 = fmaf(erow[i + 0], g_B[(i + 0) * DD + j2], a0);
      a1 = fmaf(erow[i + 1], g_B[(i + 1) * DD + j2], a1);
      a2 = fmaf(erow[i + 2], g_B[(i + 2) * DD + j2], a2);
      a3 = fmaf(erow[i + 3], g_B[(i + 3) * DD + j2], a3);
    }
    float sum = (a0 + a1) + (a2 + a3);
    __syncthreads();
    if (h == 1) part[j2] = sum;
    __syncthreads();
    if (h == 0) {
      sum += part[j2];
      unsigned short hi = f2bf(sum);
      unsigned short lo = f2bf(sum - bf2f(hi));
      g_Qh[j1 * DD + j2] = hi;
      g_Ql[j1 * DD + j2] = lo;
    }
  }
  tree_barrier(bid);

  // ---- P5: quad, 2 tiles of 64 t's (R9 MFMA body) ----
  int lane = tid & 63;
  int w = tid >> 6;
  int lrow = lane & 15;
  int lgrp = lane >> 4;
  #pragma unroll 1
  for (int k = 0; k < 2; ++k) {
    int tau = bid * 2 + k;            // 0..1023
    int b = tau >> 6;
    int t0 = (tau & 63) * 64;
    const float* xb = x + (size_t)b * NC * LIN;
    __syncthreads();                  // xs reuse across k
    for (int idx = tid; idx < NC * 71; idx += 256) {
      int c = idx / 71, o = idx % 71;
      int g = t0 + o;
      xs[c][o] = (g < LIN) ? xb[c * LIN + g] : 0.0f;
    }
    __syncthreads();

    f32x4 acc[8];
    #pragma unroll
    for (int n = 0; n < 8; ++n) acc[n] = (f32x4){0.f, 0.f, 0.f, 0.f};

    #pragma unroll
    for (int kb = 0; kb < 4; ++kb) {
      int c = kb * 4 + lgrp;
      int tl = w * 16 + lrow;
      bf16x8 a_hi, a_lo;
      #pragma unroll
      for (int e = 0; e < 8; ++e) {
        float v = xs[c][tl + e];
        unsigned short hh = f2bf(v);
        unsigned short ll = f2bf(v - bf2f(hh));
        a_hi[e] = (short)hh;
        a_lo[e] = (short)ll;
      }
      #pragma unroll
      for (int n = 0; n < 8; ++n) {
        int off = (n * 16 + lrow) * DD + kb * 32 + lgrp * 8;
        bf16x8 b_hi = *(const bf16x8*)(g_Qh + off);
        bf16x8 b_lo = *(const bf16x8*)(g_Ql + off);
        acc[n] = __builtin_amdgcn_mfma_f32_16x16x32_bf16(a_hi, b_hi, acc[n], 0, 0, 0);
        acc[n] = __builtin_amdgcn_mfma_f32_16x16x32_bf16(a_hi, b_lo, acc[n], 0, 0, 0);
        acc[n] = __builtin_amdgcn_mfma_f32_16x16x32_bf16(a_lo, b_hi, acc[n], 0, 0, 0);
      }
    }

    float pd[4] = {0.f, 0.f, 0.f, 0.f};
    float pn[4] = {0.f, 0.f, 0.f, 0.f};
    #pragma unroll
    for (int n = 0; n < 8; ++n) {
      int i = n * 16 + lrow;
      int cc = i >> 3, ko = i & 7;
      #pragma unroll
      for (int r = 0; r < 4; ++r) {
        int tl = w * 16 + lgrp * 4 + r;
        float v = xs[cc][tl + ko];
        pd[r] = fmaf(acc[n][r], v, pd[r]);
        pn[r] = fmaf(v, v, pn[r]);
      }
    }
    #pragma unroll
    for (int r = 0; r < 4; ++r) {
      #pragma unroll
      for (int m = 1; m < 16; m <<= 1) {
        pd[r] += __shfl_xor(pd[r], m);
        pn[r] += __shfl_xor(pn[r], m);
      }
    }
    if (lrow == 0) {
      #pragma unroll
      for (int r = 0; r < 4; ++r) {
        int t = t0 + w * 16 + lgrp * 4 + r;
        if (t < LOUT) out[(size_t)b * LOUT + t] = pd[r] / (pn[r] + 1e-12f);
      }
    }
  }
}

// ---------------------------------------------------------------------------

extern "C" void kernel_launch(void* const* d_in, const int* in_sizes, int n_in,
                              void* d_out, int out_size, void* d_ws, size_t ws_size,
                              hipStream_t stream) {
  const float* x     = (const float*)d_in[0];   // (16,16,4096) f32
  const float* E     = (const float*)d_in[1];   // (512,512)    f32
  const float* theta = (const float*)d_in[2];   // (3,9)        f32
  float* out = (float*)d_out;                   // (16,1,1,4089) f32
  (void)d_ws; (void)ws_size;

  fused_kernel<<<NBLK, 256, 0, stream>>>(x, E, theta, out);
}

// Round 12
// 92.939 us; speedup vs baseline: 4.3056x; 4.3056x over previous
//
#include <hip/hip_runtime.h>
#include <math.h>

// Problem constants
#define QDIM 512     // 2^9 state dim
#define DD   128     // K*C_IN = input dim of quadratic form
#define LIN  4096
#define LOUT 4089    // (4096 - 7 - 1)/1 + 1
#define NC   16      // C_IN
#define NB   16      // batch

typedef __attribute__((ext_vector_type(8))) short bf16x8;
typedef __attribute__((ext_vector_type(4))) float f32x4;

// Scratch in device globals (NOT d_ws) — R5 lesson. Every element rewritten
// each call before read. R8+R11 lesson: NO persistent-grid barriers — the
// agent-scope fences/spin-loads L2-invalidate chip-wide (R11: 6.7GB refetch).
__device__ float  g_B[QDIM * DD];          // A, row-major [i][j]
__device__ unsigned short g_Qh[DD * DD];   // bf16 hi part of Q
__device__ unsigned short g_Ql[DD * DD];   // bf16 residual of Q

// ---- bf16 helpers (RNE) ----
__device__ __forceinline__ unsigned short f2bf(float f) {
  union { float f; unsigned u; } v; v.f = f;
  unsigned u = v.u + 0x7FFFu + ((v.u >> 16) & 1u);
  return (unsigned short)(u >> 16);
}
__device__ __forceinline__ float bf2f(unsigned short h) {
  union { unsigned u; float f; } v; v.u = ((unsigned)h) << 16;
  return v.f;
}

// ---------------------------------------------------------------------------
// colA: A[:,j] = E*R3*E*R2*E*R1*e_j — column chains are INDEPENDENT, so the
// whole precompute-to-A pipeline is one kernel, no grid-wide dependencies.
// 64 blocks x 2 columns. Vector lives in LDS; forward butterflies (reference
// order q=0..8, [[c,-s],[s,c]]); E-matvec via 16-lane groups: coalesced
// float4 E row reads, v-slices preloaded to VGPRs, shfl_xor reduce.
// ---------------------------------------------------------------------------

__device__ __forceinline__ void butterfly_F2(float v[2][QDIM],
                                             const float* theta, int l, int p) {
  #pragma unroll
  for (int q = 0; q < 9; ++q) {        // forward order
    float half = theta[l * 9 + q] * 0.5f;
    float c = cosf(half), s = sinf(half);
    int right = QDIM >> (q + 1);
    int a = p >> (8 - q);
    int r = p & (right - 1);
    int i0 = (a * 2) * right + r;
    int i1 = i0 + right;
    #pragma unroll
    for (int m = 0; m < 2; ++m) {
      float x0 = v[m][i0], x1 = v[m][i1];
      v[m][i0] = c * x0 - s * x1;      // forward 2x2
      v[m][i1] = s * x0 + c * x1;
    }
    __syncthreads();
  }
}

__device__ __forceinline__ void matvecE2(const float* __restrict__ E,
                                         const float src[2][QDIM],
                                         float dst[2][QDIM], int tid) {
  int gid = tid >> 4, gl = tid & 15;
  // preload this lane's column slice of src (same for all rows)
  float4 vr0[8], vr1[8];
  #pragma unroll
  for (int cc = 0; cc < 8; ++cc) {
    int c0 = cc * 64 + gl * 4;
    vr0[cc] = *(const float4*)&src[0][c0];
    vr1[cc] = *(const float4*)&src[1][c0];
  }
  #pragma unroll 2
  for (int rr = 0; rr < 32; ++rr) {
    int row = rr * 16 + gid;           // wave covers 4 consecutive rows
    const float4* er = (const float4*)&E[(size_t)row * QDIM];
    float a0 = 0.f, a1 = 0.f;
    #pragma unroll
    for (int cc = 0; cc < 8; ++cc) {
      float4 ev = er[cc * 16 + gl];
      a0 = fmaf(ev.x, vr0[cc].x, a0); a0 = fmaf(ev.y, vr0[cc].y, a0);
      a0 = fmaf(ev.z, vr0[cc].z, a0); a0 = fmaf(ev.w, vr0[cc].w, a0);
      a1 = fmaf(ev.x, vr1[cc].x, a1); a1 = fmaf(ev.y, vr1[cc].y, a1);
      a1 = fmaf(ev.z, vr1[cc].z, a1); a1 = fmaf(ev.w, vr1[cc].w, a1);
    }
    #pragma unroll
    for (int m = 1; m < 16; m <<= 1) {
      a0 += __shfl_xor(a0, m);
      a1 += __shfl_xor(a1, m);
    }
    if (gl == 0) { dst[0][row] = a0; dst[1][row] = a1; }
  }
}

__global__ __launch_bounds__(256) void colA_kernel(const float* __restrict__ E,
                                                   const float* __restrict__ theta) {
  __shared__ float v[2][QDIM];
  __shared__ float u[2][QDIM];
  int j0 = blockIdx.x * 2;
  int tid = threadIdx.x;
  v[0][tid] = (tid == j0) ? 1.0f : 0.0f;
  v[0][tid + 256] = 0.0f;
  v[1][tid] = (tid == j0 + 1) ? 1.0f : 0.0f;
  v[1][tid + 256] = 0.0f;
  __syncthreads();
  butterfly_F2(v, theta, 0, tid);      // ends with sync
  matvecE2(E, v, u, tid);
  __syncthreads();
  butterfly_F2(u, theta, 1, tid);
  matvecE2(E, u, v, tid);
  __syncthreads();
  butterfly_F2(v, theta, 2, tid);
  matvecE2(E, v, u, tid);
  __syncthreads();
  #pragma unroll
  for (int m = 0; m < 2; ++m) {
    g_B[(size_t)tid * DD + j0 + m]         = u[m][tid];
    g_B[(size_t)(tid + 256) * DD + j0 + m] = u[m][tid + 256];
  }
}

// ---------------------------------------------------------------------------
// formq (verbatim R9): Q[j1][j2] = sum_i sgn(i) A[i][j1] A[i][j2]; A = g_B.
// ---------------------------------------------------------------------------
__global__ __launch_bounds__(256) void formq_kernel() {
  const float* A = g_B;
  __shared__ float colA[QDIM];
  __shared__ float part[DD];
  int j1 = blockIdx.x;
  int tid = threadIdx.x;
  int j2 = tid & 127, h = tid >> 7;
  for (int i = tid; i < QDIM; i += 256) {
    float sgn = (i < 256) ? 1.0f : -1.0f;
    colA[i] = sgn * A[i * DD + j1];
  }
  __syncthreads();
  float a0 = 0.f, a1 = 0.f, a2 = 0.f, a3 = 0.f;
  int i0 = h * 256;
  #pragma unroll 8
  for (int i = i0; i < i0 + 256; i += 4) {
    a0 = fmaf(colA[i + 0], A[(i + 0) * DD + j2], a0);
    a1 = fmaf(colA[i + 1], A[(i + 1) * DD + j2], a1);
    a2 = fmaf(colA[i + 2], A[(i + 2) * DD + j2], a2);
    a3 = fmaf(colA[i + 3], A[(i + 3) * DD + j2], a3);
  }
  float sum = (a0 + a1) + (a2 + a3);
  if (h == 1) part[j2] = sum;
  __syncthreads();
  if (h == 0) {
    sum += part[j2];
    unsigned short hi = f2bf(sum);
    unsigned short lo = f2bf(sum - bf2f(hi));
    g_Qh[j1 * DD + j2] = hi;
    g_Ql[j1 * DD + j2] = lo;
  }
}

// ---------------------------------------------------------------------------
// quad (verbatim R9): MFMA split-bf16, 64-t tile, 4 waves x (16t x 128i).
// ---------------------------------------------------------------------------
__global__ __launch_bounds__(256, 4) void quad_mfma_kernel(const float* __restrict__ x,
                                                           float* __restrict__ out) {
  __shared__ float xs[NC][72];      // 71 used (64 t + 7 halo)
  int b = blockIdx.x;
  int t0 = blockIdx.y * 64;
  int tid = threadIdx.x;
  int lane = tid & 63;
  int w = tid >> 6;
  const float* xb = x + (size_t)b * NC * LIN;

  for (int idx = tid; idx < NC * 71; idx += 256) {
    int c = idx / 71, o = idx % 71;
    int g = t0 + o;
    xs[c][o] = (g < LIN) ? xb[c * LIN + g] : 0.0f;
  }
  __syncthreads();

  int lrow = lane & 15;
  int lgrp = lane >> 4;

  f32x4 acc[8];
  #pragma unroll
  for (int n = 0; n < 8; ++n) acc[n] = (f32x4){0.f, 0.f, 0.f, 0.f};

  #pragma unroll
  for (int kb = 0; kb < 4; ++kb) {
    int c = kb * 4 + lgrp;
    int tl = w * 16 + lrow;
    bf16x8 a_hi, a_lo;
    #pragma unroll
    for (int e = 0; e < 8; ++e) {
      float v = xs[c][tl + e];
      unsigned short hh = f2bf(v);
      unsigned short ll = f2bf(v - bf2f(hh));
      a_hi[e] = (short)hh;
      a_lo[e] = (short)ll;
    }
    #pragma unroll
    for (int n = 0; n < 8; ++n) {
      int off = (n * 16 + lrow) * DD + kb * 32 + lgrp * 8;
      bf16x8 b_hi = *(const bf16x8*)(g_Qh + off);
      bf16x8 b_lo = *(const bf16x8*)(g_Ql + off);
      acc[n] = __builtin_amdgcn_mfma_f32_16x16x32_bf16(a_hi, b_hi, acc[n], 0, 0, 0);
      acc[n] = __builtin_amdgcn_mfma_f32_16x16x32_bf16(a_hi, b_lo, acc[n], 0, 0, 0);
      acc[n] = __builtin_amdgcn_mfma_f32_16x16x32_bf16(a_lo, b_hi, acc[n], 0, 0, 0);
    }
  }

  float pd[4] = {0.f, 0.f, 0.f, 0.f};
  float pn[4] = {0.f, 0.f, 0.f, 0.f};
  #pragma unroll
  for (int n = 0; n < 8; ++n) {
    int i = n * 16 + lrow;
    int cc = i >> 3, ko = i & 7;
    #pragma unroll
    for (int r = 0; r < 4; ++r) {
      int tl = w * 16 + lgrp * 4 + r;
      float v = xs[cc][tl + ko];
      pd[r] = fmaf(acc[n][r], v, pd[r]);
      pn[r] = fmaf(v, v, pn[r]);
    }
  }
  #pragma unroll
  for (int r = 0; r < 4; ++r) {
    #pragma unroll
    for (int m = 1; m < 16; m <<= 1) {
      pd[r] += __shfl_xor(pd[r], m);
      pn[r] += __shfl_xor(pn[r], m);
    }
  }
  if (lrow == 0) {
    #pragma unroll
    for (int r = 0; r < 4; ++r) {
      int t = t0 + w * 16 + lgrp * 4 + r;
      if (t < LOUT) out[(size_t)b * LOUT + t] = pd[r] / (pn[r] + 1e-12f);
    }
  }
}

// ---------------------------------------------------------------------------

extern "C" void kernel_launch(void* const* d_in, const int* in_sizes, int n_in,
                              void* d_out, int out_size, void* d_ws, size_t ws_size,
                              hipStream_t stream) {
  const float* x     = (const float*)d_in[0];   // (16,16,4096) f32
  const float* E     = (const float*)d_in[1];   // (512,512)    f32
  const float* theta = (const float*)d_in[2];   // (3,9)        f32
  float* out = (float*)d_out;                   // (16,1,1,4089) f32
  (void)d_ws; (void)ws_size;

  colA_kernel<<<DD / 2, 256, 0, stream>>>(E, theta);   // -> g_B (A, 512x128)
  formq_kernel<<<DD, 256, 0, stream>>>();              // -> g_Qh/g_Ql
  quad_mfma_kernel<<<dim3(NB, 64), 256, 0, stream>>>(x, out);
}

// Round 15
// 84.339 us; speedup vs baseline: 4.7446x; 1.1020x over previous
//
#include <hip/hip_runtime.h>
#include <math.h>

// Problem constants
#define QDIM 512     // 2^9 state dim
#define DD   128     // K*C_IN = input dim of quadratic form
#define LIN  4096
#define LOUT 4089    // (4096 - 7 - 1)/1 + 1
#define NC   16      // C_IN
#define NB   16      // batch

typedef __attribute__((ext_vector_type(8))) short bf16x8;
typedef __attribute__((ext_vector_type(4))) float f32x4;

// Scratch in device globals (NOT d_ws) — R5 lesson. Every element rewritten
// each call before read. R8+R11 lesson: NO persistent-grid barriers.
// R14 lesson: 512-thread epilogue writes ONE element per thread (the
// carried-over tid+256 write was 131KB OOB -> core dump).
__device__ float  g_B[QDIM * DD];          // A, row-major [i][j]
__device__ unsigned short g_Qh[DD * DD];   // bf16 hi part of Q
__device__ unsigned short g_Ql[DD * DD];   // bf16 residual of Q

// ---- bf16 helpers (RNE) ----
__device__ __forceinline__ unsigned short f2bf(float f) {
  union { float f; unsigned u; } v; v.f = f;
  unsigned u = v.u + 0x7FFFu + ((v.u >> 16) & 1u);
  return (unsigned short)(u >> 16);
}
__device__ __forceinline__ float bf2f(unsigned short h) {
  union { unsigned u; float f; } v; v.u = ((unsigned)h) << 16;
  return v.f;
}

// ---------------------------------------------------------------------------
// colA v2: A[:,j] = E*R3*E*R2*E*R1*e_j. One column per block, 512 threads.
// Wave-private reg vector (i = lane*8+e); shfl butterflies (no barriers);
// matvec: wave w computes rows [w*64,w*64+64), coalesced float4 E reads,
// unroll 4, xor-reduce; 2 barriers/stage.
// ---------------------------------------------------------------------------
__global__ __launch_bounds__(512) void colA_kernel(const float* __restrict__ E,
                                                   const float* __restrict__ theta) {
  __shared__ float vbuf[QDIM];
  int j = blockIdx.x;
  int tid = threadIdx.x;
  int lane = tid & 63;
  int wid = tid >> 6;

  float myv[8];
  #pragma unroll
  for (int e = 0; e < 8; ++e) myv[e] = (lane * 8 + e == j) ? 1.0f : 0.0f;

  #pragma unroll 1
  for (int l = 0; l < 3; ++l) {
    // ---- forward RY butterflies (qubit q <-> bit 8-q), in registers ----
    #pragma unroll
    for (int q = 0; q < 9; ++q) {
      float half = theta[l * 9 + q] * 0.5f;
      float c = cosf(half), s = sinf(half);
      int bit = 8 - q;
      if (bit >= 3) {
        int m = 1 << (bit - 3);            // lane-crossing
        bool up = (lane & m) != 0;
        #pragma unroll
        for (int e = 0; e < 8; ++e) {
          float pv = __shfl_xor(myv[e], m);
          myv[e] = up ? fmaf(s, pv, c * myv[e]) : fmaf(-s, pv, c * myv[e]);
        }
      } else {
        int m = 1 << bit;                  // in-register pairs
        #pragma unroll
        for (int e = 0; e < 8; ++e) {
          if (!(e & m)) {
            float x0 = myv[e], x1 = myv[e | m];
            myv[e]     = fmaf(-s, x1, c * x0);
            myv[e | m] = fmaf(s, x0, c * x1);
          }
        }
      }
    }
    // ---- matvec u = E * v : wave computes rows [wid*64, wid*64+64) ----
    __syncthreads();                       // prior vbuf reads complete
    #pragma unroll 1
    for (int rr = 0; rr < 64; rr += 4) {
      float sum0, sum1, sum2, sum3;
      {
        const float4* er0 = (const float4*)&E[(size_t)(wid * 64 + rr + 0) * QDIM];
        const float4* er1 = (const float4*)&E[(size_t)(wid * 64 + rr + 1) * QDIM];
        const float4* er2 = (const float4*)&E[(size_t)(wid * 64 + rr + 2) * QDIM];
        const float4* er3 = (const float4*)&E[(size_t)(wid * 64 + rr + 3) * QDIM];
        float4 a0 = er0[lane * 2], b0 = er0[lane * 2 + 1];
        float4 a1 = er1[lane * 2], b1 = er1[lane * 2 + 1];
        float4 a2 = er2[lane * 2], b2 = er2[lane * 2 + 1];
        float4 a3 = er3[lane * 2], b3 = er3[lane * 2 + 1];
        sum0 = a0.x * myv[0]; sum1 = a1.x * myv[0];
        sum2 = a2.x * myv[0]; sum3 = a3.x * myv[0];
        sum0 = fmaf(a0.y, myv[1], sum0); sum1 = fmaf(a1.y, myv[1], sum1);
        sum2 = fmaf(a2.y, myv[1], sum2); sum3 = fmaf(a3.y, myv[1], sum3);
        sum0 = fmaf(a0.z, myv[2], sum0); sum1 = fmaf(a1.z, myv[2], sum1);
        sum2 = fmaf(a2.z, myv[2], sum2); sum3 = fmaf(a3.z, myv[2], sum3);
        sum0 = fmaf(a0.w, myv[3], sum0); sum1 = fmaf(a1.w, myv[3], sum1);
        sum2 = fmaf(a2.w, myv[3], sum2); sum3 = fmaf(a3.w, myv[3], sum3);
        sum0 = fmaf(b0.x, myv[4], sum0); sum1 = fmaf(b1.x, myv[4], sum1);
        sum2 = fmaf(b2.x, myv[4], sum2); sum3 = fmaf(b3.x, myv[4], sum3);
        sum0 = fmaf(b0.y, myv[5], sum0); sum1 = fmaf(b1.y, myv[5], sum1);
        sum2 = fmaf(b2.y, myv[5], sum2); sum3 = fmaf(b3.y, myv[5], sum3);
        sum0 = fmaf(b0.z, myv[6], sum0); sum1 = fmaf(b1.z, myv[6], sum1);
        sum2 = fmaf(b2.z, myv[6], sum2); sum3 = fmaf(b3.z, myv[6], sum3);
        sum0 = fmaf(b0.w, myv[7], sum0); sum1 = fmaf(b1.w, myv[7], sum1);
        sum2 = fmaf(b2.w, myv[7], sum2); sum3 = fmaf(b3.w, myv[7], sum3);
      }
      #pragma unroll
      for (int m = 1; m < 64; m <<= 1) {
        sum0 += __shfl_xor(sum0, m);
        sum1 += __shfl_xor(sum1, m);
        sum2 += __shfl_xor(sum2, m);
        sum3 += __shfl_xor(sum3, m);
      }
      if (lane == 0) {
        int bq = wid * 64 + rr;
        vbuf[bq + 0] = sum0; vbuf[bq + 1] = sum1;
        vbuf[bq + 2] = sum2; vbuf[bq + 3] = sum3;
      }
    }
    __syncthreads();
    #pragma unroll
    for (int e = 0; e < 8; ++e) myv[e] = vbuf[lane * 8 + e];
  }
  // vbuf holds A[:, j]; one element per thread (512 threads = 512 rows)
  g_B[(size_t)tid * DD + j] = vbuf[tid];
}

// ---------------------------------------------------------------------------
// formq (verbatim R9): Q[j1][j2] = sum_i sgn(i) A[i][j1] A[i][j2]; A = g_B.
// ---------------------------------------------------------------------------
__global__ __launch_bounds__(256) void formq_kernel() {
  const float* A = g_B;
  __shared__ float colA[QDIM];
  __shared__ float part[DD];
  int j1 = blockIdx.x;
  int tid = threadIdx.x;
  int j2 = tid & 127, h = tid >> 7;
  for (int i = tid; i < QDIM; i += 256) {
    float sgn = (i < 256) ? 1.0f : -1.0f;
    colA[i] = sgn * A[i * DD + j1];
  }
  __syncthreads();
  float a0 = 0.f, a1 = 0.f, a2 = 0.f, a3 = 0.f;
  int i0 = h * 256;
  #pragma unroll 8
  for (int i = i0; i < i0 + 256; i += 4) {
    a0 = fmaf(colA[i + 0], A[(i + 0) * DD + j2], a0);
    a1 = fmaf(colA[i + 1], A[(i + 1) * DD + j2], a1);
    a2 = fmaf(colA[i + 2], A[(i + 2) * DD + j2], a2);
    a3 = fmaf(colA[i + 3], A[(i + 3) * DD + j2], a3);
  }
  float sum = (a0 + a1) + (a2 + a3);
  if (h == 1) part[j2] = sum;
  __syncthreads();
  if (h == 0) {
    sum += part[j2];
    unsigned short hi = f2bf(sum);
    unsigned short lo = f2bf(sum - bf2f(hi));
    g_Qh[j1 * DD + j2] = hi;
    g_Ql[j1 * DD + j2] = lo;
  }
}

// ---------------------------------------------------------------------------
// quad (verbatim R9): MFMA split-bf16, 64-t tile, 4 waves x (16t x 128i).
// ---------------------------------------------------------------------------
__global__ __launch_bounds__(256, 4) void quad_mfma_kernel(const float* __restrict__ x,
                                                           float* __restrict__ out) {
  __shared__ float xs[NC][72];      // 71 used (64 t + 7 halo)
  int b = blockIdx.x;
  int t0 = blockIdx.y * 64;
  int tid = threadIdx.x;
  int lane = tid & 63;
  int w = tid >> 6;
  const float* xb = x + (size_t)b * NC * LIN;

  for (int idx = tid; idx < NC * 71; idx += 256) {
    int c = idx / 71, o = idx % 71;
    int g = t0 + o;
    xs[c][o] = (g < LIN) ? xb[c * LIN + g] : 0.0f;
  }
  __syncthreads();

  int lrow = lane & 15;
  int lgrp = lane >> 4;

  f32x4 acc[8];
  #pragma unroll
  for (int n = 0; n < 8; ++n) acc[n] = (f32x4){0.f, 0.f, 0.f, 0.f};

  #pragma unroll
  for (int kb = 0; kb < 4; ++kb) {
    int c = kb * 4 + lgrp;
    int tl = w * 16 + lrow;
    bf16x8 a_hi, a_lo;
    #pragma unroll
    for (int e = 0; e < 8; ++e) {
      float v = xs[c][tl + e];
      unsigned short hh = f2bf(v);
      unsigned short ll = f2bf(v - bf2f(hh));
      a_hi[e] = (short)hh;
      a_lo[e] = (short)ll;
    }
    #pragma unroll
    for (int n = 0; n < 8; ++n) {
      int off = (n * 16 + lrow) * DD + kb * 32 + lgrp * 8;
      bf16x8 b_hi = *(const bf16x8*)(g_Qh + off);
      bf16x8 b_lo = *(const bf16x8*)(g_Ql + off);
      acc[n] = __builtin_amdgcn_mfma_f32_16x16x32_bf16(a_hi, b_hi, acc[n], 0, 0, 0);
      acc[n] = __builtin_amdgcn_mfma_f32_16x16x32_bf16(a_hi, b_lo, acc[n], 0, 0, 0);
      acc[n] = __builtin_amdgcn_mfma_f32_16x16x32_bf16(a_lo, b_hi, acc[n], 0, 0, 0);
    }
  }

  float pd[4] = {0.f, 0.f, 0.f, 0.f};
  float pn[4] = {0.f, 0.f, 0.f, 0.f};
  #pragma unroll
  for (int n = 0; n < 8; ++n) {
    int i = n * 16 + lrow;
    int cc = i >> 3, ko = i & 7;
    #pragma unroll
    for (int r = 0; r < 4; ++r) {
      int tl = w * 16 + lgrp * 4 + r;
      float v = xs[cc][tl + ko];
      pd[r] = fmaf(acc[n][r], v, pd[r]);
      pn[r] = fmaf(v, v, pn[r]);
    }
  }
  #pragma unroll
  for (int r = 0; r < 4; ++r) {
    #pragma unroll
    for (int m = 1; m < 16; m <<= 1) {
      pd[r] += __shfl_xor(pd[r], m);
      pn[r] += __shfl_xor(pn[r], m);
    }
  }
  if (lrow == 0) {
    #pragma unroll
    for (int r = 0; r < 4; ++r) {
      int t = t0 + w * 16 + lgrp * 4 + r;
      if (t < LOUT) out[(size_t)b * LOUT + t] = pd[r] / (pn[r] + 1e-12f);
    }
  }
}

// ---------------------------------------------------------------------------

extern "C" void kernel_launch(void* const* d_in, const int* in_sizes, int n_in,
                              void* d_out, int out_size, void* d_ws, size_t ws_size,
                              hipStream_t stream) {
  const float* x     = (const float*)d_in[0];   // (16,16,4096) f32
  const float* E     = (const float*)d_in[1];   // (512,512)    f32
  const float* theta = (const float*)d_in[2];   // (3,9)        f32
  float* out = (float*)d_out;                   // (16,1,1,4089) f32
  (void)d_ws; (void)ws_size;

  colA_kernel<<<DD, 512, 0, stream>>>(E, theta);   // -> g_B (A, 512x128)
  formq_kernel<<<DD, 256, 0, stream>>>();          // -> g_Qh/g_Ql
  quad_mfma_kernel<<<dim3(NB, 64), 256, 0, stream>>>(x, out);
}